// Round 1
// baseline (6110.648 us; speedup 1.0000x reference)
//
#include <hip/hip_runtime.h>
#include <math.h>

#define TPB 256

// ---------------------------------------------------------------------------
// degree count (same for all layers: depends only on dst)
// ---------------------------------------------------------------------------
__global__ void count_kernel(const int* __restrict__ dst, float* __restrict__ cnt, int E) {
    int e = blockIdx.x * blockDim.x + threadIdx.x;
    if (e < E) atomicAdd(&cnt[dst[e]], 1.0f);
}

__global__ void inv_kernel(float* cnt, int N) {
    int n = blockIdx.x * blockDim.x + threadIdx.x;
    if (n < N) cnt[n] = 1.0f / fmaxf(cnt[n], 1.0f);
}

// ---------------------------------------------------------------------------
// XJ = h @ g   (node-level: [N, cin] @ [cin, 3*cout] -> [N, 3*cout])
// thread per output element; consecutive threads share row n -> g loads coalesced
// ---------------------------------------------------------------------------
__global__ void xj_kernel(const float* __restrict__ h, const float* __restrict__ g,
                          float* __restrict__ xj, int N, int cin, int cols) {
    int idx = blockIdx.x * blockDim.x + threadIdx.x;
    if (idx >= N * cols) return;
    int n = idx / cols;
    int c = idx - n * cols;
    float acc = 0.f;
    for (int i = 0; i < cin; ++i) acc += h[n * cin + i] * g[i * cols + c];
    xj[idx] = acc;
}

// ---------------------------------------------------------------------------
// edge kernel: gaussian mixture weights + gather XJ[src] + atomic scatter to agg[dst]
// K = 3 kernels, D = 3 pseudo-coord dims (fixed by the problem)
// ---------------------------------------------------------------------------
template<int COUT>
__global__ void edge_kernel(const int* __restrict__ src, const int* __restrict__ dst,
                            const float* __restrict__ ea,
                            const float* __restrict__ mu, const float* __restrict__ sigma,
                            const float* __restrict__ xj, float* __restrict__ agg, int E) {
    __shared__ float s_mu[9];
    __shared__ float s_gs[9];   // -0.5 / (eps + sigma^2)
    int t = threadIdx.x;
    if (t < 9) {
        s_mu[t] = mu[t];
        float sg = sigma[t];
        s_gs[t] = -0.5f / (1e-15f + sg * sg);
    }
    __syncthreads();

    int e = blockIdx.x * blockDim.x + t;
    if (e >= E) return;

    int s = src[e];
    int d = dst[e];
    float u0 = ea[(size_t)e * 3 + 0];
    float u1 = ea[(size_t)e * 3 + 1];
    float u2 = ea[(size_t)e * 3 + 2];

    float gk[3];
#pragma unroll
    for (int k = 0; k < 3; ++k) {
        float d0 = u0 - s_mu[k * 3 + 0];
        float d1 = u1 - s_mu[k * 3 + 1];
        float d2 = u2 - s_mu[k * 3 + 2];
        gk[k] = __expf(d0 * d0 * s_gs[k * 3 + 0] +
                       d1 * d1 * s_gs[k * 3 + 1] +
                       d2 * d2 * s_gs[k * 3 + 2]);
    }

    const float* xr = xj + (size_t)s * (3 * COUT);
    float* ar = agg + (size_t)d * COUT;
#pragma unroll
    for (int o = 0; o < COUT; ++o) {
        float m = gk[0] * xr[o] + gk[1] * xr[COUT + o] + gk[2] * xr[2 * COUT + o];
        atomicAdd(&ar[o], m);
    }
}

// ---------------------------------------------------------------------------
// finalize: out = [elu]( agg * inv_cnt + h @ root + b )
// ---------------------------------------------------------------------------
template<int CIN, int COUT, bool ELU>
__global__ void finalize_kernel(const float* __restrict__ h, const float* __restrict__ agg,
                                const float* __restrict__ inv, const float* __restrict__ root,
                                const float* __restrict__ b, float* __restrict__ out, int N) {
    int idx = blockIdx.x * blockDim.x + threadIdx.x;
    if (idx >= N * COUT) return;
    int n = idx / COUT;
    int o = idx - n * COUT;
    float acc = agg[idx] * inv[n] + b[o];
#pragma unroll
    for (int c = 0; c < CIN; ++c) acc += h[n * CIN + c] * root[c * COUT + o];
    if (ELU && acc < 0.f) acc = __expf(acc) - 1.0f;
    out[idx] = acc;
}

// ---------------------------------------------------------------------------
// host-side per-layer driver
// ---------------------------------------------------------------------------
template<int CIN, int COUT, bool ELU>
static void launch_layer(const float* hin,
                         const float* g, const float* mu, const float* sigma,
                         const float* root, const float* b,
                         const int* src, const int* dst, const float* ea,
                         float* XJ, float* agg, const float* inv,
                         float* hout, int N, int E, hipStream_t stream) {
    hipMemsetAsync(agg, 0, (size_t)N * COUT * sizeof(float), stream);
    const int cols = 3 * COUT;
    int nxj = N * cols;
    xj_kernel<<<(nxj + TPB - 1) / TPB, TPB, 0, stream>>>(hin, g, XJ, N, CIN, cols);
    edge_kernel<COUT><<<(E + TPB - 1) / TPB, TPB, 0, stream>>>(src, dst, ea, mu, sigma, XJ, agg, E);
    int nfin = N * COUT;
    finalize_kernel<CIN, COUT, ELU><<<(nfin + TPB - 1) / TPB, TPB, 0, stream>>>(
        hin, agg, inv, root, b, hout, N);
}

extern "C" void kernel_launch(void* const* d_in, const int* in_sizes, int n_in,
                              void* d_out, int out_size, void* d_ws, size_t ws_size,
                              hipStream_t stream) {
    const float* x  = (const float*)d_in[0];
    const int*   ei = (const int*)d_in[1];
    const float* ea = (const float*)d_in[2];

    const int N = in_sizes[0] / 3;
    const int E = in_sizes[2] / 3;
    const int* src = ei;
    const int* dst = ei + E;

    // per-layer params: g, mu, sigma, root, b starting at index 3
    const float* g1 = (const float*)d_in[3];  const float* mu1 = (const float*)d_in[4];
    const float* s1 = (const float*)d_in[5];  const float* r1  = (const float*)d_in[6];
    const float* b1 = (const float*)d_in[7];
    const float* g2 = (const float*)d_in[8];  const float* mu2 = (const float*)d_in[9];
    const float* s2 = (const float*)d_in[10]; const float* r2  = (const float*)d_in[11];
    const float* b2 = (const float*)d_in[12];
    const float* g3 = (const float*)d_in[13]; const float* mu3 = (const float*)d_in[14];
    const float* s3 = (const float*)d_in[15]; const float* r3  = (const float*)d_in[16];
    const float* b3 = (const float*)d_in[17];
    const float* g4 = (const float*)d_in[18]; const float* mu4 = (const float*)d_in[19];
    const float* s4 = (const float*)d_in[20]; const float* r4  = (const float*)d_in[21];
    const float* b4 = (const float*)d_in[22];

    // workspace layout (floats)
    float* ws  = (float*)d_ws;
    float* hA  = ws;                          // N*16
    float* hB  = hA + (size_t)N * 16;         // N*16
    float* XJ  = hB + (size_t)N * 16;         // N*48
    float* agg = XJ + (size_t)N * 48;         // N*16
    float* inv = agg + (size_t)N * 16;        // N  (cnt, then inverted in place)

    // degree counts (shared by all layers)
    hipMemsetAsync(inv, 0, (size_t)N * sizeof(float), stream);
    count_kernel<<<(E + TPB - 1) / TPB, TPB, 0, stream>>>(dst, inv, E);
    inv_kernel<<<(N + TPB - 1) / TPB, TPB, 0, stream>>>(inv, N);

    float* out = (float*)d_out;

    // layer 1: x[3] -> hA[8], elu
    launch_layer<3, 8, true >(x,  g1, mu1, s1, r1, b1, src, dst, ea, XJ, agg, inv, hA, N, E, stream);
    // layer 2: hA[8] -> hB[16], elu
    launch_layer<8, 16, true >(hA, g2, mu2, s2, r2, b2, src, dst, ea, XJ, agg, inv, hB, N, E, stream);
    // layer 3: hB[16] -> hA[8], elu
    launch_layer<16, 8, true >(hB, g3, mu3, s3, r3, b3, src, dst, ea, XJ, agg, inv, hA, N, E, stream);
    // layer 4: hA[8] -> out[4], no elu
    launch_layer<8, 4, false>(hA, g4, mu4, s4, r4, b4, src, dst, ea, XJ, agg, inv, out, N, E, stream);
}

// Round 2
// 994.745 us; speedup vs baseline: 6.1429x; 6.1429x over previous
//
#include <hip/hip_runtime.h>
#include <math.h>

#define TPB 256
#define SCAN_T 1024

// ---------------------------------------------------------------------------
// Phase 0: CSR-by-dst build (once per call, shared by all 4 layers)
// ---------------------------------------------------------------------------
__global__ void count_kernel(const int* __restrict__ dst, int* __restrict__ cnt, int E) {
    int e = blockIdx.x * blockDim.x + threadIdx.x;
    if (e < E) atomicAdd(&cnt[dst[e]], 1);
}

// single-workgroup scan: cnt -> rowptr (exclusive); cnt array becomes the fill cursor
__global__ void scan_kernel(int* __restrict__ cnt_cursor, int* __restrict__ rowptr, int N, int E) {
    __shared__ int part[SCAN_T];
    int t = threadIdx.x;
    int C = (N + SCAN_T - 1) / SCAN_T;
    int lo = t * C; if (lo > N) lo = N;
    int hi = lo + C; if (hi > N) hi = N;
    int s = 0;
    for (int i = lo; i < hi; ++i) s += cnt_cursor[i];
    part[t] = s;
    __syncthreads();
    for (int off = 1; off < SCAN_T; off <<= 1) {
        int v = (t >= off) ? part[t - off] : 0;
        __syncthreads();
        part[t] += v;
        __syncthreads();
    }
    int base = part[t] - s;   // exclusive prefix
    for (int i = lo; i < hi; ++i) {
        int c = cnt_cursor[i];
        rowptr[i] = base;
        cnt_cursor[i] = base;   // re-init as cursor for fill_kernel
        base += c;
    }
    if (t == SCAN_T - 1) rowptr[N] = E;
}

// scatter edges into dst-bucketed order; one float4 record = {ea0, ea1, ea2, src-as-int}
__global__ void fill_kernel(const int* __restrict__ src, const int* __restrict__ dst,
                            const float* __restrict__ ea, int* __restrict__ cursor,
                            float4* __restrict__ perm, int E) {
    int e = blockIdx.x * blockDim.x + threadIdx.x;
    if (e >= E) return;
    int d = dst[e];
    int pos = atomicAdd(&cursor[d], 1);
    float4 p;
    p.x = ea[(size_t)e * 3 + 0];
    p.y = ea[(size_t)e * 3 + 1];
    p.z = ea[(size_t)e * 3 + 2];
    p.w = __int_as_float(src[e]);
    perm[pos] = p;
}

// ---------------------------------------------------------------------------
// Fused per-layer kernel: thread = (node, channel).
// out[n,o] = elu( (1/max(deg,1)) * sum_e gauss_k(e) * (h[src_e] @ g)[k,o]
//                 + h[n] @ root[:,o] + b[o] )
// g-columns for this thread's o (3*CIN floats) live in registers.
// ---------------------------------------------------------------------------
template<int CIN, int COUT, bool ELU>
__global__ void layer_kernel(const float* __restrict__ h,
                             const float* __restrict__ g,      // [CIN, 3*COUT]
                             const float* __restrict__ mu, const float* __restrict__ sigma,
                             const float* __restrict__ root,   // [CIN, COUT]
                             const float* __restrict__ bias,
                             const int* __restrict__ rowptr,
                             const float4* __restrict__ perm,
                             float* __restrict__ out, int N) {
    constexpr int NPB = TPB / COUT;
    __shared__ float s_mu[9], s_gs[9];
    int t = threadIdx.x;
    if (t < 9) {
        s_mu[t] = mu[t];
        float sg = sigma[t];
        s_gs[t] = -0.5f / (1e-15f + sg * sg);
    }
    __syncthreads();

    int n = blockIdx.x * NPB + t / COUT;
    int o = t % COUT;
    if (n >= N) return;

    // per-thread g columns: gc[i][k] = g[i][k*COUT + o]
    float gc[CIN][3];
#pragma unroll
    for (int i = 0; i < CIN; ++i)
#pragma unroll
        for (int k = 0; k < 3; ++k)
            gc[i][k] = g[i * 3 * COUT + k * COUT + o];

    int e0 = rowptr[n], e1 = rowptr[n + 1];
    float acc = 0.f;
    for (int e = e0; e < e1; ++e) {
        float4 p = perm[e];
        int s = __float_as_int(p.w);
        float w[3];
#pragma unroll
        for (int k = 0; k < 3; ++k) {
            float d0 = p.x - s_mu[3 * k + 0];
            float d1 = p.y - s_mu[3 * k + 1];
            float d2 = p.z - s_mu[3 * k + 2];
            w[k] = __expf(d0 * d0 * s_gs[3 * k + 0] +
                          d1 * d1 * s_gs[3 * k + 1] +
                          d2 * d2 * s_gs[3 * k + 2]);
        }
        const float* hr = h + (size_t)s * CIN;
#pragma unroll
        for (int i = 0; i < CIN; ++i) {
            float wef = gc[i][0] * w[0] + gc[i][1] * w[1] + gc[i][2] * w[2];
            acc += hr[i] * wef;
        }
    }

    float deg = (float)(e1 - e0);
    acc /= fmaxf(deg, 1.0f);
    acc += bias[o];
    const float* hn = h + (size_t)n * CIN;
#pragma unroll
    for (int i = 0; i < CIN; ++i) acc += hn[i] * root[i * COUT + o];
    if (ELU && acc < 0.f) acc = __expf(acc) - 1.0f;
    out[(size_t)n * COUT + o] = acc;
}

// ---------------------------------------------------------------------------
template<int CIN, int COUT, bool ELU>
static void launch_layer(const float* hin, const float* g, const float* mu,
                         const float* sigma, const float* root, const float* b,
                         const int* rowptr, const float4* perm,
                         float* hout, int N, hipStream_t stream) {
    int blocks = (N * COUT + TPB - 1) / TPB;
    layer_kernel<CIN, COUT, ELU><<<blocks, TPB, 0, stream>>>(
        hin, g, mu, sigma, root, b, rowptr, perm, hout, N);
}

extern "C" void kernel_launch(void* const* d_in, const int* in_sizes, int n_in,
                              void* d_out, int out_size, void* d_ws, size_t ws_size,
                              hipStream_t stream) {
    const float* x  = (const float*)d_in[0];
    const int*   ei = (const int*)d_in[1];
    const float* ea = (const float*)d_in[2];

    const int N = in_sizes[0] / 3;
    const int E = in_sizes[2] / 3;
    const int* src = ei;
    const int* dst = ei + E;

    const float* g1 = (const float*)d_in[3];  const float* mu1 = (const float*)d_in[4];
    const float* s1 = (const float*)d_in[5];  const float* r1  = (const float*)d_in[6];
    const float* b1 = (const float*)d_in[7];
    const float* g2 = (const float*)d_in[8];  const float* mu2 = (const float*)d_in[9];
    const float* s2 = (const float*)d_in[10]; const float* r2  = (const float*)d_in[11];
    const float* b2 = (const float*)d_in[12];
    const float* g3 = (const float*)d_in[13]; const float* mu3 = (const float*)d_in[14];
    const float* s3 = (const float*)d_in[15]; const float* r3  = (const float*)d_in[16];
    const float* b3 = (const float*)d_in[17];
    const float* g4 = (const float*)d_in[18]; const float* mu4 = (const float*)d_in[19];
    const float* s4 = (const float*)d_in[20]; const float* r4  = (const float*)d_in[21];
    const float* b4 = (const float*)d_in[22];

    // workspace layout
    char* w = (char*)d_ws;
    int* rowptr = (int*)w;                    // N+1 ints
    int* cursor = rowptr + (N + 1);           // N ints (cnt, then cursor)
    size_t off = ((size_t)(2 * N + 1) * 4 + 15) & ~(size_t)15;
    float4* perm = (float4*)(w + off);        // E float4
    float* hA = (float*)(perm + E);           // N*16
    float* hB = hA + (size_t)N * 16;          // N*16

    // CSR build
    hipMemsetAsync(cursor, 0, (size_t)N * sizeof(int), stream);
    count_kernel<<<(E + TPB - 1) / TPB, TPB, 0, stream>>>(dst, cursor, E);
    scan_kernel<<<1, SCAN_T, 0, stream>>>(cursor, rowptr, N, E);
    fill_kernel<<<(E + TPB - 1) / TPB, TPB, 0, stream>>>(src, dst, ea, cursor, perm, E);

    float* out = (float*)d_out;

    launch_layer<3, 8, true >(x,  g1, mu1, s1, r1, b1, rowptr, perm, hA, N, stream);
    launch_layer<8, 16, true >(hA, g2, mu2, s2, r2, b2, rowptr, perm, hB, N, stream);
    launch_layer<16, 8, true >(hB, g3, mu3, s3, r3, b3, rowptr, perm, hA, N, stream);
    launch_layer<8, 4, false>(hA, g4, mu4, s4, r4, b4, rowptr, perm, out, N, stream);
}

// Round 3
// 783.094 us; speedup vs baseline: 7.8032x; 1.2703x over previous
//
#include <hip/hip_runtime.h>
#include <math.h>

#define TPB 256
#define CHUNK 1024   // elements per scan block

// ---------------------------------------------------------------------------
// Phase 0: CSR-by-dst build (once per call, shared by all 4 layers)
// ---------------------------------------------------------------------------
__global__ void count_kernel(const int* __restrict__ dst, int* __restrict__ cnt, int E) {
    int e = blockIdx.x * blockDim.x + threadIdx.x;
    if (e < E) atomicAdd(&cnt[dst[e]], 1);
}

// 3-phase device-wide exclusive scan of cnt[N] -> rowptr[N+1], cursor[N]
__global__ void partial_kernel(const int* __restrict__ cnt, int* __restrict__ partials, int N) {
    __shared__ int red[TPB];
    int base = blockIdx.x * CHUNK;
    int t = threadIdx.x;
    int s = 0;
    for (int i = t; i < CHUNK; i += TPB) {
        int idx = base + i;
        if (idx < N) s += cnt[idx];
    }
    red[t] = s;
    __syncthreads();
    for (int off = TPB / 2; off > 0; off >>= 1) {
        if (t < off) red[t] += red[t + off];
        __syncthreads();
    }
    if (t == 0) partials[blockIdx.x] = red[0];
}

__global__ void scan_partials_kernel(int* __restrict__ partials, int P) {
    __shared__ int buf[1024];
    int t = threadIdx.x;
    int v = (t < P) ? partials[t] : 0;
    buf[t] = v;
    __syncthreads();
    for (int off = 1; off < 1024; off <<= 1) {
        int u = (t >= off) ? buf[t - off] : 0;
        __syncthreads();
        buf[t] += u;
        __syncthreads();
    }
    if (t < P) partials[t] = buf[t] - v;   // exclusive
}

__global__ void rowptr_kernel(const int* __restrict__ cnt, const int* __restrict__ partials,
                              int* __restrict__ rowptr, int* __restrict__ cursor, int N, int E) {
    __shared__ int tsum[TPB];
    int base = blockIdx.x * CHUNK;
    int t = threadIdx.x;
    int idx0 = base + t * 4;
    int c[4];
    int s = 0;
#pragma unroll
    for (int j = 0; j < 4; ++j) {
        int i = idx0 + j;
        c[j] = (i < N) ? cnt[i] : 0;
        s += c[j];
    }
    tsum[t] = s;
    __syncthreads();
    for (int off = 1; off < TPB; off <<= 1) {
        int u = (t >= off) ? tsum[t - off] : 0;
        __syncthreads();
        tsum[t] += u;
        __syncthreads();
    }
    int run = partials[blockIdx.x] + tsum[t] - s;   // exclusive start
#pragma unroll
    for (int j = 0; j < 4; ++j) {
        int i = idx0 + j;
        if (i < N) {
            rowptr[i] = run;
            cursor[i] = run;
            run += c[j];
        }
    }
    if (blockIdx.x == 0 && t == 0) rowptr[N] = E;
}

// scatter edges into dst-bucketed order; one float4 record = {ea0, ea1, ea2, src-as-int}
__global__ void fill_kernel(const int* __restrict__ src, const int* __restrict__ dst,
                            const float* __restrict__ ea, int* __restrict__ cursor,
                            float4* __restrict__ perm, int E) {
    int e = blockIdx.x * blockDim.x + threadIdx.x;
    if (e >= E) return;
    int d = dst[e];
    int pos = atomicAdd(&cursor[d], 1);
    float4 p;
    p.x = ea[(size_t)e * 3 + 0];
    p.y = ea[(size_t)e * 3 + 1];
    p.z = ea[(size_t)e * 3 + 2];
    p.w = __int_as_float(src[e]);
    perm[pos] = p;
}

// ---------------------------------------------------------------------------
// Fused per-layer kernel: thread = (node, channel).
// ---------------------------------------------------------------------------
template<int CIN, int COUT, bool ELU>
__global__ void layer_kernel(const float* __restrict__ h,
                             const float* __restrict__ g,      // [CIN, 3*COUT]
                             const float* __restrict__ mu, const float* __restrict__ sigma,
                             const float* __restrict__ root,   // [CIN, COUT]
                             const float* __restrict__ bias,
                             const int* __restrict__ rowptr,
                             const float4* __restrict__ perm,
                             float* __restrict__ out, int N) {
    constexpr int NPB = TPB / COUT;
    __shared__ float s_mu[9], s_gs[9];
    int t = threadIdx.x;
    if (t < 9) {
        s_mu[t] = mu[t];
        float sg = sigma[t];
        s_gs[t] = -0.5f / (1e-15f + sg * sg);
    }
    __syncthreads();

    int n = blockIdx.x * NPB + t / COUT;
    int o = t % COUT;
    if (n >= N) return;

    float gc[CIN][3];
#pragma unroll
    for (int i = 0; i < CIN; ++i)
#pragma unroll
        for (int k = 0; k < 3; ++k)
            gc[i][k] = g[i * 3 * COUT + k * COUT + o];

    int e0 = rowptr[n], e1 = rowptr[n + 1];
    float acc = 0.f;
    for (int e = e0; e < e1; ++e) {
        float4 p = perm[e];
        int s = __float_as_int(p.w);
        float w[3];
#pragma unroll
        for (int k = 0; k < 3; ++k) {
            float d0 = p.x - s_mu[3 * k + 0];
            float d1 = p.y - s_mu[3 * k + 1];
            float d2 = p.z - s_mu[3 * k + 2];
            w[k] = __expf(d0 * d0 * s_gs[3 * k + 0] +
                          d1 * d1 * s_gs[3 * k + 1] +
                          d2 * d2 * s_gs[3 * k + 2]);
        }
        const float* hr = h + (size_t)s * CIN;
#pragma unroll
        for (int i = 0; i < CIN; ++i) {
            float wef = gc[i][0] * w[0] + gc[i][1] * w[1] + gc[i][2] * w[2];
            acc += hr[i] * wef;
        }
    }

    float deg = (float)(e1 - e0);
    acc /= fmaxf(deg, 1.0f);
    acc += bias[o];
    const float* hn = h + (size_t)n * CIN;
#pragma unroll
    for (int i = 0; i < CIN; ++i) acc += hn[i] * root[i * COUT + o];
    if (ELU && acc < 0.f) acc = __expf(acc) - 1.0f;
    out[(size_t)n * COUT + o] = acc;
}

// ---------------------------------------------------------------------------
template<int CIN, int COUT, bool ELU>
static void launch_layer(const float* hin, const float* g, const float* mu,
                         const float* sigma, const float* root, const float* b,
                         const int* rowptr, const float4* perm,
                         float* hout, int N, hipStream_t stream) {
    int blocks = (N * COUT + TPB - 1) / TPB;
    layer_kernel<CIN, COUT, ELU><<<blocks, TPB, 0, stream>>>(
        hin, g, mu, sigma, root, b, rowptr, perm, hout, N);
}

extern "C" void kernel_launch(void* const* d_in, const int* in_sizes, int n_in,
                              void* d_out, int out_size, void* d_ws, size_t ws_size,
                              hipStream_t stream) {
    const float* x  = (const float*)d_in[0];
    const int*   ei = (const int*)d_in[1];
    const float* ea = (const float*)d_in[2];

    const int N = in_sizes[0] / 3;
    const int E = in_sizes[2] / 3;
    const int* src = ei;
    const int* dst = ei + E;

    const float* g1 = (const float*)d_in[3];  const float* mu1 = (const float*)d_in[4];
    const float* s1 = (const float*)d_in[5];  const float* r1  = (const float*)d_in[6];
    const float* b1 = (const float*)d_in[7];
    const float* g2 = (const float*)d_in[8];  const float* mu2 = (const float*)d_in[9];
    const float* s2 = (const float*)d_in[10]; const float* r2  = (const float*)d_in[11];
    const float* b2 = (const float*)d_in[12];
    const float* g3 = (const float*)d_in[13]; const float* mu3 = (const float*)d_in[14];
    const float* s3 = (const float*)d_in[15]; const float* r3  = (const float*)d_in[16];
    const float* b3 = (const float*)d_in[17];
    const float* g4 = (const float*)d_in[18]; const float* mu4 = (const float*)d_in[19];
    const float* s4 = (const float*)d_in[20]; const float* r4  = (const float*)d_in[21];
    const float* b4 = (const float*)d_in[22];

    // workspace layout
    const int P = (N + CHUNK - 1) / CHUNK;           // scan blocks (98 for N=100K)
    char* w = (char*)d_ws;
    int* rowptr   = (int*)w;                          // N+1
    int* cursor   = rowptr + (N + 1);                 // N
    int* partials = cursor + N;                       // P (<=1024)
    size_t off = (((size_t)(2 * N + 1) + 1024) * 4 + 15) & ~(size_t)15;
    float4* perm = (float4*)(w + off);                // E
    float* hA = (float*)(perm + E);                   // N*16
    float* hB = hA + (size_t)N * 16;                  // N*16

    // CSR build
    hipMemsetAsync(cursor, 0, (size_t)N * sizeof(int), stream);
    count_kernel<<<(E + TPB - 1) / TPB, TPB, 0, stream>>>(dst, cursor, E);
    partial_kernel<<<P, TPB, 0, stream>>>(cursor, partials, N);
    scan_partials_kernel<<<1, 1024, 0, stream>>>(partials, P);
    rowptr_kernel<<<P, TPB, 0, stream>>>(cursor, partials, rowptr, cursor, N, E);
    fill_kernel<<<(E + TPB - 1) / TPB, TPB, 0, stream>>>(src, dst, ea, cursor, perm, E);

    float* out = (float*)d_out;

    launch_layer<3, 8, true >(x,  g1, mu1, s1, r1, b1, rowptr, perm, hA, N, stream);
    launch_layer<8, 16, true >(hA, g2, mu2, s2, r2, b2, rowptr, perm, hB, N, stream);
    launch_layer<16, 8, true >(hB, g3, mu3, s3, r3, b3, rowptr, perm, hA, N, stream);
    launch_layer<8, 4, false>(hA, g4, mu4, s4, r4, b4, rowptr, perm, out, N, stream);
}